// Round 1
// 90.178 us; speedup vs baseline: 1.0283x; 1.0283x over previous
//
#include <hip/hip_runtime.h>
#include <cstddef>

#define NDET 32
#define ME   128   // max electrons (n_e)
#define MN   128   // nuclei
#define NOUT (NDET * ME)   // 4096 orbital columns
#define LOG2E 1.4426950408889634f

#if __has_builtin(__builtin_amdgcn_exp2f)
#define EXP2(x) __builtin_amdgcn_exp2f(x)
#else
#define EXP2(x) exp2f(x)
#endif

typedef float v2f __attribute__((ext_vector_type(2)));

// One block: fixed (spin s, det d), 16 electrons (e0..e0+15), all 128 j.
// 512 threads: j = tid&127, g = tid>>7 (wave-uniform).
//   h  = g&1  -> which 8-electron half this thread accumulates
//   nh = g>>1 -> which 64-nucleus half this thread sums over
// Splitting the n-loop doubles wave-parallelism (2 -> 4 waves/SIMD) so the
// quarter-rate transcendental pipe (8 exp2 per wave-iter) stays fed; the
// nh=1 partials are reduced into nh=0 through the retired duv buffer.
// (zeta,pi) computed as one packed-f32 dot chain per n, amortized over 8
// outputs; duv stores -dist*log2e so the negate is pre-folded.
__global__ __launch_bounds__(512) void env_kernel(
    const float* __restrict__ up_coords,
    const float* __restrict__ down_coords,
    const float* __restrict__ nuc_coords,
    const float* __restrict__ nuc_charges,
    const float* __restrict__ W_pi_up,
    const float* __restrict__ W_zeta_up,
    const float* __restrict__ W_pi_down,
    const float* __restrict__ W_zeta_down,
    float* __restrict__ out)
{
    __shared__ float4 feats4[MN];     // (charge, cx, cy, cz); centered before main loop
    __shared__ float  duv[MN * 16];   // [n][16 local electrons]: -dist * log2e; reused as reduce buf
    __shared__ float  ecl[16 * 3];    // this block's electron coords
    __shared__ float  msum[2][3];     // per-wave partial coord sums

    const int tid = (int)threadIdx.x;
    const int e0  = (int)blockIdx.x * 16;
    const int d   = (int)blockIdx.y;
    const int s   = (int)blockIdx.z;

    const float* ec = s ? down_coords : up_coords;
    const float* We = s ? W_pi_down   : W_pi_up;    // exponent factors (zeta = feats@W_pi)
    const float* Ww = s ? W_zeta_down : W_zeta_up;  // nuclear weights  (pi   = feats@W_zeta)

    // Phase 1: stage raw nuclear data + this block's electron coords.
    if (tid < MN) {
        feats4[tid] = make_float4(nuc_charges[tid],
                                  nuc_coords[tid * 3 + 0],
                                  nuc_coords[tid * 3 + 1],
                                  nuc_coords[tid * 3 + 2]);
    } else if (tid < MN + 48) {
        ecl[tid - MN] = ec[e0 * 3 + (tid - MN)];
    }
    __syncthreads();

    // Mean of nuclear coords via shuffle butterfly on waves 0,1 (masks all-true).
    if (tid < MN) {
        float4 f = feats4[tid];
        float sx = f.y, sy = f.z, sz = f.w;
        #pragma unroll
        for (int off = 32; off > 0; off >>= 1) {
            sx += __shfl_xor(sx, off);
            sy += __shfl_xor(sy, off);
            sz += __shfl_xor(sz, off);
        }
        if ((tid & 63) == 0) {
            const int w = tid >> 6;
            msum[w][0] = sx; msum[w][1] = sy; msum[w][2] = sz;
        }
    }
    __syncthreads();

    const float mx = (msum[0][0] + msum[1][0]) * (1.f / MN);
    const float my = (msum[0][1] + msum[1][1]) * (1.f / MN);
    const float mz = (msum[0][2] + msum[1][2]) * (1.f / MN);

    // Phase 2: du table (negated, log2e-scaled). Thread t: n = t>>2, quarter q = t&3.
    {
        const int n = tid >> 2;
        const int q = tid & 3;
        const float4 f = feats4[n];   // raw (uncentered) nucleus coords
        float r[4];
        #pragma unroll
        for (int i = 0; i < 4; ++i) {
            const int e = q * 4 + i;
            const float dx = ecl[e * 3 + 0] - f.y;
            const float dy = ecl[e * 3 + 1] - f.z;
            const float dz = ecl[e * 3 + 2] - f.w;
            r[i] = sqrtf(fmaf(dx, dx, fmaf(dy, dy, dz * dz))) * (-LOG2E);
        }
        *(float4*)&duv[n * 16 + q * 4] = make_float4(r[0], r[1], r[2], r[3]);
    }
    __syncthreads();

    // Phase 3: center nuclear coords in place.
    if (tid < MN) {
        float4 f = feats4[tid];
        feats4[tid] = make_float4(f.x, f.y - mx, f.z - my, f.w - mz);
    }
    __syncthreads();

    // Main loop: 64 nuclei per thread (nh picks the half).
    const int j  = tid & 127;
    const int g  = tid >> 7;         // wave-uniform
    const int h  = g & 1;            // electron half
    const int nh = g >> 1;           // nucleus half
    const int o  = d * ME + j;

    // Packed weights: .x -> zeta path (W_pi), .y -> pi path (W_zeta).
    const v2f w0 = { We[0*NOUT+o], Ww[0*NOUT+o] };
    const v2f w1 = { We[1*NOUT+o], Ww[1*NOUT+o] };
    const v2f w2 = { We[2*NOUT+o], Ww[2*NOUT+o] };
    const v2f w3 = { We[3*NOUT+o], Ww[3*NOUT+o] };

    v2f acc01 = {0.f, 0.f}, acc23 = {0.f, 0.f}, acc45 = {0.f, 0.f}, acc67 = {0.f, 0.f};

    const float4* du4 = (const float4*)duv;
    const int nbeg = nh * 64;
    #pragma unroll 8
    for (int n = nbeg; n < nbeg + 64; ++n) {
        const float4 f = feats4[n];                                   // LDS broadcast
        // zp.x = zeta, zp.y = pi  (contracted to v_pk_fma_f32)
        v2f zp = f.x * w0 + (f.y * w1 + (f.z * w2 + f.w * w3));
        const float az = __builtin_fabsf(zp.x);
        const v2f az2 = {az, az};
        const v2f pi2 = {zp.y, zp.y};
        const float4 u0 = du4[n * 4 + h * 2 + 0];                     // LDS broadcast
        const float4 u1 = du4[n * 4 + h * 2 + 1];                     // LDS broadcast
        v2f t01 = (v2f){u0.x, u0.y} * az2;   // du already negated
        v2f t23 = (v2f){u0.z, u0.w} * az2;
        v2f t45 = (v2f){u1.x, u1.y} * az2;
        v2f t67 = (v2f){u1.z, u1.w} * az2;
        t01.x = EXP2(t01.x); t01.y = EXP2(t01.y);
        t23.x = EXP2(t23.x); t23.y = EXP2(t23.y);
        t45.x = EXP2(t45.x); t45.y = EXP2(t45.y);
        t67.x = EXP2(t67.x); t67.y = EXP2(t67.y);
        acc01 = acc01 + pi2 * t01;
        acc23 = acc23 + pi2 * t23;
        acc45 = acc45 + pi2 * t45;
        acc67 = acc67 + pi2 * t67;
    }

    // Reduce nh=1 partials into nh=0 through the retired duv buffer.
    __syncthreads();                 // all waves done reading duv/feats4
    if (nh) {
        float4* r = (float4*)&duv[(h * 128 + j) * 8];
        r[0] = make_float4(acc01.x, acc01.y, acc23.x, acc23.y);
        r[1] = make_float4(acc45.x, acc45.y, acc67.x, acc67.y);
    }
    __syncthreads();
    if (!nh) {
        const float4* r = (const float4*)&duv[(h * 128 + j) * 8];
        const float4 p0 = r[0];
        const float4 p1 = r[1];
        // out[s][d][e][j], e = e0 + 8h + i
        const int e_base = e0 + h * 8;
        float* op = out + ((((size_t)s * NDET + d) * ME + e_base) * ME + j);
        op[0 * ME] = acc01.x + p0.x;
        op[1 * ME] = acc01.y + p0.y;
        op[2 * ME] = acc23.x + p0.z;
        op[3 * ME] = acc23.y + p0.w;
        op[4 * ME] = acc45.x + p1.x;
        op[5 * ME] = acc45.y + p1.y;
        op[6 * ME] = acc67.x + p1.z;
        op[7 * ME] = acc67.y + p1.w;
    }
}

extern "C" void kernel_launch(void* const* d_in, const int* in_sizes, int n_in,
                              void* d_out, int out_size, void* d_ws, size_t ws_size,
                              hipStream_t stream)
{
    (void)in_sizes; (void)n_in; (void)out_size; (void)d_ws; (void)ws_size;
    env_kernel<<<dim3(8, 32, 2), 512, 0, stream>>>(
        (const float*)d_in[0],   // up_coords
        (const float*)d_in[1],   // down_coords
        (const float*)d_in[2],   // nuc_coords
        (const float*)d_in[3],   // nuc_charges
        (const float*)d_in[4],   // W_pi_up
        (const float*)d_in[5],   // W_zeta_up
        (const float*)d_in[6],   // W_pi_down
        (const float*)d_in[7],   // W_zeta_down
        (float*)d_out);
}

// Round 2
// 89.777 us; speedup vs baseline: 1.0329x; 1.0045x over previous
//
#include <hip/hip_runtime.h>
#include <cstddef>

#define NDET 32
#define ME   128   // max electrons (n_e)
#define MN   128   // nuclei
#define EBLK 8     // electrons per block
#define NOUT (NDET * ME)   // 4096 orbital columns
#define LOG2E 1.4426950408889634f

#if __has_builtin(__builtin_amdgcn_exp2f)
#define EXP2(x) __builtin_amdgcn_exp2f(x)
#else
#define EXP2(x) exp2f(x)
#endif

typedef float v2f __attribute__((ext_vector_type(2)));

// One block: fixed (spin s, det d), 8 electrons (e0..e0+7), all 128 j.
// 512 threads: j = tid&127, g = tid>>7 in [0,4) picks a 32-nucleus quarter.
// Every thread accumulates all 8 block electrons over its quarter; quarters
// g=1..3 dump partials to LDS and g=0 reduces + stores. Grid = 1024 blocks
// -> 8 waves/SIMD (launch_bounds caps VGPR at 64) so the quarter-rate
// transcendental pipe (8 exp2 per wave-iter behind a serial FMA chain)
// stays saturated. duv stores -dist*log2e so the negate is pre-folded;
// (zeta,pi) is one packed-f32 dot chain per n amortized over 8 outputs.
__global__ __launch_bounds__(512, 8) void env_kernel(
    const float* __restrict__ up_coords,
    const float* __restrict__ down_coords,
    const float* __restrict__ nuc_coords,
    const float* __restrict__ nuc_charges,
    const float* __restrict__ W_pi_up,
    const float* __restrict__ W_zeta_up,
    const float* __restrict__ W_pi_down,
    const float* __restrict__ W_zeta_down,
    float* __restrict__ out)
{
    __shared__ float4 feats4[MN];         // 2 KB: (charge, cx, cy, cz); centered before main loop
    __shared__ float  duv[MN * EBLK];     // 4 KB: [n][8 electrons]: -dist * log2e
    __shared__ float  ecl[EBLK * 3];      // this block's electron coords
    __shared__ float  msum[2][3];         // per-wave partial coord sums
    __shared__ float4 red[3][128][2];     // 12 KB: partials from quarters 1..3

    const int tid = (int)threadIdx.x;
    const int e0  = (int)blockIdx.x * EBLK;
    const int d   = (int)blockIdx.y;
    const int s   = (int)blockIdx.z;

    const float* ec = s ? down_coords : up_coords;
    const float* We = s ? W_pi_down   : W_pi_up;    // exponent factors (zeta = feats@W_pi)
    const float* Ww = s ? W_zeta_down : W_zeta_up;  // nuclear weights  (pi   = feats@W_zeta)

    // Phase 1: stage raw nuclear data + this block's electron coords.
    if (tid < MN) {
        feats4[tid] = make_float4(nuc_charges[tid],
                                  nuc_coords[tid * 3 + 0],
                                  nuc_coords[tid * 3 + 1],
                                  nuc_coords[tid * 3 + 2]);
    } else if (tid < MN + EBLK * 3) {
        ecl[tid - MN] = ec[e0 * 3 + (tid - MN)];
    }
    __syncthreads();

    // Mean of nuclear coords via shuffle butterfly on waves 0,1 (masks all-true).
    if (tid < MN) {
        float4 f = feats4[tid];
        float sx = f.y, sy = f.z, sz = f.w;
        #pragma unroll
        for (int off = 32; off > 0; off >>= 1) {
            sx += __shfl_xor(sx, off);
            sy += __shfl_xor(sy, off);
            sz += __shfl_xor(sz, off);
        }
        if ((tid & 63) == 0) {
            const int w = tid >> 6;
            msum[w][0] = sx; msum[w][1] = sy; msum[w][2] = sz;
        }
    }
    __syncthreads();

    const float mx = (msum[0][0] + msum[1][0]) * (1.f / MN);
    const float my = (msum[0][1] + msum[1][1]) * (1.f / MN);
    const float mz = (msum[0][2] + msum[1][2]) * (1.f / MN);

    // Phase 2: du table (negated, log2e-scaled). Thread t: n = t>>2, pair q = t&3.
    {
        const int n = tid >> 2;
        const int q = tid & 3;
        const float4 f = feats4[n];   // raw (uncentered) nucleus coords
        float r[2];
        #pragma unroll
        for (int i = 0; i < 2; ++i) {
            const int e = q * 2 + i;
            const float dx = ecl[e * 3 + 0] - f.y;
            const float dy = ecl[e * 3 + 1] - f.z;
            const float dz = ecl[e * 3 + 2] - f.w;
            r[i] = sqrtf(fmaf(dx, dx, fmaf(dy, dy, dz * dz))) * (-LOG2E);
        }
        *(float2*)&duv[n * EBLK + q * 2] = make_float2(r[0], r[1]);
    }
    __syncthreads();

    // Phase 3: center nuclear coords in place.
    if (tid < MN) {
        float4 f = feats4[tid];
        feats4[tid] = make_float4(f.x, f.y - mx, f.z - my, f.w - mz);
    }
    __syncthreads();

    // Main loop: 32 nuclei per thread (quarter g).
    const int j = tid & 127;
    const int g = tid >> 7;          // wave-uniform quarter
    const int o = d * ME + j;

    // Packed weights: .x -> zeta path (W_pi), .y -> pi path (W_zeta).
    const v2f w0 = { We[0*NOUT+o], Ww[0*NOUT+o] };
    const v2f w1 = { We[1*NOUT+o], Ww[1*NOUT+o] };
    const v2f w2 = { We[2*NOUT+o], Ww[2*NOUT+o] };
    const v2f w3 = { We[3*NOUT+o], Ww[3*NOUT+o] };

    v2f acc01 = {0.f, 0.f}, acc23 = {0.f, 0.f}, acc45 = {0.f, 0.f}, acc67 = {0.f, 0.f};

    const float4* du4 = (const float4*)duv;
    const int nbeg = g * 32;
    #pragma unroll 8
    for (int n = nbeg; n < nbeg + 32; ++n) {
        const float4 f = feats4[n];                                   // LDS broadcast
        // zp.x = zeta, zp.y = pi  (contracted to v_pk_fma_f32)
        v2f zp = f.x * w0 + (f.y * w1 + (f.z * w2 + f.w * w3));
        const float az = __builtin_fabsf(zp.x);
        const v2f az2 = {az, az};
        const v2f pi2 = {zp.y, zp.y};
        const float4 u0 = du4[n * 2 + 0];                             // LDS broadcast
        const float4 u1 = du4[n * 2 + 1];                             // LDS broadcast
        v2f t01 = (v2f){u0.x, u0.y} * az2;   // du already negated
        v2f t23 = (v2f){u0.z, u0.w} * az2;
        v2f t45 = (v2f){u1.x, u1.y} * az2;
        v2f t67 = (v2f){u1.z, u1.w} * az2;
        t01.x = EXP2(t01.x); t01.y = EXP2(t01.y);
        t23.x = EXP2(t23.x); t23.y = EXP2(t23.y);
        t45.x = EXP2(t45.x); t45.y = EXP2(t45.y);
        t67.x = EXP2(t67.x); t67.y = EXP2(t67.y);
        acc01 = acc01 + pi2 * t01;
        acc23 = acc23 + pi2 * t23;
        acc45 = acc45 + pi2 * t45;
        acc67 = acc67 + pi2 * t67;
    }

    // Quarters 1..3 dump partials; quarter 0 reduces and stores.
    if (g) {
        red[g - 1][j][0] = make_float4(acc01.x, acc01.y, acc23.x, acc23.y);
        red[g - 1][j][1] = make_float4(acc45.x, acc45.y, acc67.x, acc67.y);
    }
    __syncthreads();
    if (!g) {
        float4 p0 = red[0][j][0], p1 = red[0][j][1];
        const float4 q0 = red[1][j][0], q1 = red[1][j][1];
        const float4 r0 = red[2][j][0], r1 = red[2][j][1];
        p0.x += q0.x + r0.x; p0.y += q0.y + r0.y;
        p0.z += q0.z + r0.z; p0.w += q0.w + r0.w;
        p1.x += q1.x + r1.x; p1.y += q1.y + r1.y;
        p1.z += q1.z + r1.z; p1.w += q1.w + r1.w;
        // out[s][d][e][j], e = e0 + i
        float* op = out + ((((size_t)s * NDET + d) * ME + e0) * ME + j);
        op[0 * ME] = acc01.x + p0.x;
        op[1 * ME] = acc01.y + p0.y;
        op[2 * ME] = acc23.x + p0.z;
        op[3 * ME] = acc23.y + p0.w;
        op[4 * ME] = acc45.x + p1.x;
        op[5 * ME] = acc45.y + p1.y;
        op[6 * ME] = acc67.x + p1.z;
        op[7 * ME] = acc67.y + p1.w;
    }
}

extern "C" void kernel_launch(void* const* d_in, const int* in_sizes, int n_in,
                              void* d_out, int out_size, void* d_ws, size_t ws_size,
                              hipStream_t stream)
{
    (void)in_sizes; (void)n_in; (void)out_size; (void)d_ws; (void)ws_size;
    env_kernel<<<dim3(ME / EBLK, NDET, 2), 512, 0, stream>>>(
        (const float*)d_in[0],   // up_coords
        (const float*)d_in[1],   // down_coords
        (const float*)d_in[2],   // nuc_coords
        (const float*)d_in[3],   // nuc_charges
        (const float*)d_in[4],   // W_pi_up
        (const float*)d_in[5],   // W_zeta_up
        (const float*)d_in[6],   // W_pi_down
        (const float*)d_in[7],   // W_zeta_down
        (float*)d_out);
}